// Round 1
// baseline (448.930 us; speedup 1.0000x reference)
//
#include <hip/hip_runtime.h>
#include <hip/hip_bf16.h>

// Problem: B=8, N=1024, D=256, fp32.
// out  = attn_sel @ y            [B,N,D]
// heat = selected hmap           [B,N,1]
// Pipeline: pos softmax -> t=x@U^T -> xs_k=(t*|S_k|)@U -> scores=xs@y^T*scale
//           -> blend/entropy/route (in-place attn_sel) -> out=attn_sel@y

#define NB 8
#define NN_ 1024
#define ND 256

// ---------------- reductions ----------------
__device__ inline float wred_sum(float v) {
#pragma unroll
    for (int o = 32; o; o >>= 1) v += __shfl_xor(v, o, 64);
    return v;
}
__device__ inline float wred_max(float v) {
#pragma unroll
    for (int o = 32; o; o >>= 1) v = fmaxf(v, __shfl_xor(v, o, 64));
    return v;
}
__device__ inline float bred_sum(float v, float* red) {
    v = wred_sum(v);
    int w = threadIdx.x >> 6;
    __syncthreads();
    if ((threadIdx.x & 63) == 0) red[w] = v;
    __syncthreads();
    return red[0] + red[1] + red[2] + red[3];
}
__device__ inline float bred_max(float v, float* red) {
    v = wred_max(v);
    int w = threadIdx.x >> 6;
    __syncthreads();
    if ((threadIdx.x & 63) == 0) red[w] = v;
    __syncthreads();
    return fmaxf(fmaxf(red[0], red[1]), fmaxf(red[2], red[3]));
}

// ---------------- pos softmax ----------------
// pos_logits[n,m] = -|p_temp| * sum_c coords[n,m,c]*pos_emb[n,c]; softmax over m.
__global__ __launch_bounds__(256) void pos_kernel(
    const float* __restrict__ coords, const float* __restrict__ pos_emb,
    const float* __restrict__ p_temp, float* __restrict__ posS) {
    __shared__ float red[4];
    const int n = blockIdx.x;
    const int tid = threadIdx.x;
    const float pt = -fabsf(p_temp[0]);
    float pe[6];
#pragma unroll
    for (int c = 0; c < 6; ++c) pe[c] = pos_emb[n * 6 + c];
    const float* cr = coords + (long)n * NN_ * 6;
    float l[4];
#pragma unroll
    for (int j = 0; j < 4; ++j) {
        const int m = tid * 4 + j;
        const float* cp = cr + m * 6;
        float d = 0.f;
#pragma unroll
        for (int c = 0; c < 6; ++c) d += cp[c] * pe[c];
        l[j] = pt * d;
    }
    float mx = fmaxf(fmaxf(l[0], l[1]), fmaxf(l[2], l[3]));
    mx = bred_max(mx, red);
    float e[4], s = 0.f;
#pragma unroll
    for (int j = 0; j < 4; ++j) { e[j] = expf(l[j] - mx); s += e[j]; }
    s = bred_sum(s, red);
    const float inv = 1.f / s;
    float4 o;
    o.x = e[0] * inv; o.y = e[1] * inv; o.z = e[2] * inv; o.w = e[3] * inv;
    *(float4*)(posS + (long)n * NN_ + tid * 4) = o;
}

// ---------------- generic fp32 tiled GEMM ----------------
// C[z] = alpha * A[z] * op(B[z]);  A:[M,K] rm, TRANS_B ? B:[N,K] rm : B:[K,N] rm.
// A += (z/divA)*sA1 + (z%divA)*sA2 ; B += (z/divB)*sB1 ; C += z*sC
// SCALE_K: A element at column k multiplied by |scaleK[k]|.
template <int BM, int BN, int TM, int TN, bool TRANS_B, bool SCALE_K>
__global__ __launch_bounds__(256) void gemm_kernel(
    const float* __restrict__ A, const float* __restrict__ B,
    float* __restrict__ C, const float* __restrict__ scaleK,
    int M, int N, int K,
    long sA1, long sA2, int divA, long sB1, int divB, long sC, float alpha) {
    constexpr int BKc = 8;
    const int z = blockIdx.z;
    A += (long)(z / divA) * sA1 + (long)(z % divA) * sA2;
    B += (long)(z / divB) * sB1;
    C += (long)z * sC;

    __shared__ float As[BKc][BM + 4];
    __shared__ float Bs[BKc][BN + 4];

    const int tid = threadIdx.x;
    const int bm = blockIdx.y * BM;
    const int bn = blockIdx.x * BN;
    constexpr int TX = BN / TN;
    const int tx = tid % TX;
    const int ty = tid / TX;

    float acc[TM][TN];
#pragma unroll
    for (int i = 0; i < TM; ++i)
#pragma unroll
        for (int j = 0; j < TN; ++j) acc[i][j] = 0.f;

    for (int k0 = 0; k0 < K; k0 += BKc) {
        // A tile: BM x 8 (BM==128 always here -> 1 float4/thread)
        {
            const int m = tid >> 1;
            const int kg = (tid & 1) * 4;
            float4 v = *(const float4*)(A + (long)(bm + m) * K + (k0 + kg));
            if (SCALE_K) {
                v.x *= fabsf(scaleK[k0 + kg + 0]);
                v.y *= fabsf(scaleK[k0 + kg + 1]);
                v.z *= fabsf(scaleK[k0 + kg + 2]);
                v.w *= fabsf(scaleK[k0 + kg + 3]);
            }
            As[kg + 0][m] = v.x; As[kg + 1][m] = v.y;
            As[kg + 2][m] = v.z; As[kg + 3][m] = v.w;
        }
        if (TRANS_B) {
            if (BN == 128 || tid < BN * 2) {
                const int n = tid >> 1;
                const int kg = (tid & 1) * 4;
                float4 v = *(const float4*)(B + (long)(bn + n) * K + (k0 + kg));
                Bs[kg + 0][n] = v.x; Bs[kg + 1][n] = v.y;
                Bs[kg + 2][n] = v.z; Bs[kg + 3][n] = v.w;
            }
        } else {
            if (BN == 128 || tid < BN * 2) {
                const int kk = tid / (BN / 4);
                const int n4 = (tid % (BN / 4)) * 4;
                float4 v = *(const float4*)(B + (long)(k0 + kk) * N + bn + n4);
                *(float4*)&Bs[kk][n4] = v;
            }
        }
        __syncthreads();
#pragma unroll
        for (int kk = 0; kk < BKc; ++kk) {
            float a[TM], bb[TN];
#pragma unroll
            for (int i = 0; i < TM; ++i) {
                const int r = (TM == 8) ? ((i < 4) ? ty * 4 + i : BM / 2 + ty * 4 + (i - 4))
                                        : ty * TM + i;
                a[i] = As[kk][r];
            }
#pragma unroll
            for (int j = 0; j < TN; ++j) {
                const int c = (TN == 8) ? ((j < 4) ? tx * 4 + j : BN / 2 + tx * 4 + (j - 4))
                                        : tx * TN + j;
                bb[j] = Bs[kk][c];
            }
#pragma unroll
            for (int i = 0; i < TM; ++i)
#pragma unroll
                for (int j = 0; j < TN; ++j) acc[i][j] = fmaf(a[i], bb[j], acc[i][j]);
        }
        __syncthreads();
    }
#pragma unroll
    for (int i = 0; i < TM; ++i) {
        const int r = (TM == 8) ? ((i < 4) ? ty * 4 + i : BM / 2 + ty * 4 + (i - 4))
                                : ty * TM + i;
#pragma unroll
        for (int jg = 0; jg < TN / 4; ++jg) {
            const int c = (TN == 8) ? ((jg == 0) ? tx * 4 : BN / 2 + tx * 4) : tx * TN;
            float4 v;
            v.x = acc[i][jg * 4 + 0] * alpha;
            v.y = acc[i][jg * 4 + 1] * alpha;
            v.z = acc[i][jg * 4 + 2] * alpha;
            v.w = acc[i][jg * 4 + 3] * alpha;
            *(float4*)(C + (long)(bm + r) * N + bn + c) = v;
        }
    }
}

// ---------------- blend + entropy + route (one block per (b,n) row) ----------
__global__ __launch_bounds__(256) void blend_kernel(
    float* __restrict__ S, const float* __restrict__ pos,
    const float* __restrict__ gating, const float* __restrict__ h_temp,
    float* __restrict__ heat) {
    __shared__ float red[4];
    const int bn = blockIdx.x;
    const int b = bn >> 10, n = bn & 1023;
    float* S0 = S + ((long)(b * 2 + 0) * NN_ + n) * NN_;
    const float* S1 = S + ((long)(b * 2 + 1) * NN_ + n) * NN_;
    const int tid = threadIdx.x;

    float4 l0 = *(const float4*)(S0 + tid * 4);
    float4 l1 = *(const float4*)(S1 + tid * 4);
    float4 pv = *(const float4*)(pos + (long)n * NN_ + tid * 4);

    // softmax branch 0
    float m0 = fmaxf(fmaxf(l0.x, l0.y), fmaxf(l0.z, l0.w));
    m0 = bred_max(m0, red);
    float e0x = expf(l0.x - m0), e0y = expf(l0.y - m0),
          e0z = expf(l0.z - m0), e0w = expf(l0.w - m0);
    float s0 = bred_sum(e0x + e0y + e0z + e0w, red);
    const float i0 = 1.f / s0;
    // softmax branch 1
    float m1 = fmaxf(fmaxf(l1.x, l1.y), fmaxf(l1.z, l1.w));
    m1 = bred_max(m1, red);
    float e1x = expf(l1.x - m1), e1y = expf(l1.y - m1),
          e1z = expf(l1.z - m1), e1w = expf(l1.w - m1);
    float s1 = bred_sum(e1x + e1y + e1z + e1w, red);
    const float i1 = 1.f / s1;

    const float g = 1.f / (1.f + expf(-gating[0]));
    const float cg = 1.f - g;

    float a0[4], a1[4];
    a0[0] = cg * (e0x * i0) + g * pv.x; a0[1] = cg * (e0y * i0) + g * pv.y;
    a0[2] = cg * (e0z * i0) + g * pv.z; a0[3] = cg * (e0w * i0) + g * pv.w;
    a1[0] = cg * (e1x * i1) + g * pv.x; a1[1] = cg * (e1y * i1) + g * pv.y;
    a1[2] = cg * (e1z * i1) + g * pv.z; a1[3] = cg * (e1w * i1) + g * pv.w;

    float ent0 = 0.f, ent1 = 0.f;
#pragma unroll
    for (int j = 0; j < 4; ++j) {
        ent0 -= a0[j] * logf(a0[j] + 1e-8f);
        ent1 -= a1[j] * logf(a1[j] + 1e-8f);
    }
    ent0 = bred_sum(ent0, red);
    ent1 = bred_sum(ent1, red);

    const float ht = h_temp[0];
    const float hm0 = 2.f - 2.f / (1.f + expf(-ht * ent0));
    const float hm1 = 2.f - 2.f / (1.f + expf(-ht * ent1));
    const bool fg = (hm0 >= hm1);
    if (tid == 0) heat[bn] = fg ? hm0 : hm1;

    float4 sel;
    sel.x = fg ? a0[0] : a1[0]; sel.y = fg ? a0[1] : a1[1];
    sel.z = fg ? a0[2] : a1[2]; sel.w = fg ? a0[3] : a1[3];
    *(float4*)(S0 + tid * 4) = sel;  // attn_sel in place over branch-0 row
}

extern "C" void kernel_launch(void* const* d_in, const int* in_sizes, int n_in,
                              void* d_out, int out_size, void* d_ws, size_t ws_size,
                              hipStream_t stream) {
    const float* x      = (const float*)d_in[0];
    const float* y      = (const float*)d_in[1];
    const float* coords = (const float*)d_in[2];
    const float* U      = (const float*)d_in[3];
    const float* S1p    = (const float*)d_in[4];
    const float* S2p    = (const float*)d_in[5];
    const float* gating = (const float*)d_in[6];
    const float* h_temp = (const float*)d_in[7];
    const float* p_temp = (const float*)d_in[8];
    const float* pos_emb= (const float*)d_in[9];

    float* out  = (float*)d_out;
    float* heat = out + (long)NB * NN_ * ND;  // 2097152

    float* ws  = (float*)d_ws;
    float* pos = ws;                       // 1M floats
    float* t   = pos + NN_ * NN_;          // 2M floats
    float* xs  = t + NB * NN_ * ND;        // 4M floats  [k][b*n][d]
    float* S   = xs + 2L * NB * NN_ * ND;  // 16M floats [b][k][n][m]

    const long ND2 = (long)NN_ * ND;        // 262144
    const long BND = (long)NB * NN_ * ND;   // 2097152

    // pos softmax
    pos_kernel<<<dim3(NN_), dim3(256), 0, stream>>>(coords, pos_emb, p_temp, pos);

    // t = x @ U^T   [8192,256]
    gemm_kernel<128, 64, 8, 4, true, false><<<dim3(ND / 64, (NB * NN_) / 128, 1), 256, 0, stream>>>(
        x, U, t, nullptr, NB * NN_, ND, ND, 0, 0, 1, 0, 1, 0, 1.0f);

    // xs_k = (t*|S_k|) @ U
    gemm_kernel<128, 64, 8, 4, false, true><<<dim3(ND / 64, (NB * NN_) / 128, 1), 256, 0, stream>>>(
        t, U, xs, S1p, NB * NN_, ND, ND, 0, 0, 1, 0, 1, 0, 1.0f);
    gemm_kernel<128, 64, 8, 4, false, true><<<dim3(ND / 64, (NB * NN_) / 128, 1), 256, 0, stream>>>(
        t, U, xs + BND, S2p, NB * NN_, ND, ND, 0, 0, 1, 0, 1, 0, 1.0f);

    // scores: S[b][k] = (xs_k[b] @ y[b]^T) * D^-0.5 ; z = b*2+k
    gemm_kernel<128, 128, 8, 8, true, false><<<dim3(NN_ / 128, NN_ / 128, NB * 2), 256, 0, stream>>>(
        xs, y, S, nullptr, NN_, NN_, ND,
        ND2 /*b*/, BND /*k*/, 2, ND2, 2, (long)NN_ * NN_, 0.0625f);

    // blend + entropy + route -> attn_sel into S[b][0]
    blend_kernel<<<dim3(NB * NN_), dim3(256), 0, stream>>>(S, pos, gating, h_temp, heat);

    // out[b] = attn_sel[b] @ y[b]
    gemm_kernel<128, 64, 8, 4, false, false><<<dim3(ND / 64, NN_ / 128, NB), 256, 0, stream>>>(
        S, y, out, nullptr, NN_, ND, NN_,
        2L * NN_ * NN_, 0, 1, ND2, 1, ND2, 1.0f);

    (void)in_sizes; (void)n_in; (void)out_size; (void)ws_size;
}

// Round 2
// 357.200 us; speedup vs baseline: 1.2568x; 1.2568x over previous
//
#include <hip/hip_runtime.h>
#include <hip/hip_bf16.h>

// Problem: B=8, N=1024, D=256, fp32 in/out.
// Pipeline: pos softmax -> t=x@U^T -> xs_k=(t*|S_k|)@U -> scores=xs@y^T*scale
//           -> blend/entropy/route (writes attn_sel as bf16) -> out = P@y via MFMA.
// R2: final GEMM moved to bf16 MFMA (post-routing => no route-flip risk).

#define NB 8
#define NN_ 1024
#define ND 256

typedef __bf16 bf16x8 __attribute__((ext_vector_type(8)));
typedef __bf16 bf16x4 __attribute__((ext_vector_type(4)));
typedef float f32x4 __attribute__((ext_vector_type(4)));

// ---------------- reductions ----------------
__device__ inline float wred_sum(float v) {
#pragma unroll
    for (int o = 32; o; o >>= 1) v += __shfl_xor(v, o, 64);
    return v;
}
__device__ inline float wred_max(float v) {
#pragma unroll
    for (int o = 32; o; o >>= 1) v = fmaxf(v, __shfl_xor(v, o, 64));
    return v;
}
__device__ inline float bred_sum(float v, float* red) {
    v = wred_sum(v);
    int w = threadIdx.x >> 6;
    __syncthreads();
    if ((threadIdx.x & 63) == 0) red[w] = v;
    __syncthreads();
    return red[0] + red[1] + red[2] + red[3];
}
__device__ inline float bred_max(float v, float* red) {
    v = wred_max(v);
    int w = threadIdx.x >> 6;
    __syncthreads();
    if ((threadIdx.x & 63) == 0) red[w] = v;
    __syncthreads();
    return fmaxf(fmaxf(red[0], red[1]), fmaxf(red[2], red[3]));
}

// ---------------- pos softmax ----------------
__global__ __launch_bounds__(256) void pos_kernel(
    const float* __restrict__ coords, const float* __restrict__ pos_emb,
    const float* __restrict__ p_temp, float* __restrict__ posS) {
    __shared__ float red[4];
    const int n = blockIdx.x;
    const int tid = threadIdx.x;
    const float pt = -fabsf(p_temp[0]);
    float pe[6];
#pragma unroll
    for (int c = 0; c < 6; ++c) pe[c] = pos_emb[n * 6 + c];
    const float* cr = coords + (long)n * NN_ * 6;
    float l[4];
#pragma unroll
    for (int j = 0; j < 4; ++j) {
        const int m = tid * 4 + j;
        const float* cp = cr + m * 6;
        float d = 0.f;
#pragma unroll
        for (int c = 0; c < 6; ++c) d += cp[c] * pe[c];
        l[j] = pt * d;
    }
    float mx = fmaxf(fmaxf(l[0], l[1]), fmaxf(l[2], l[3]));
    mx = bred_max(mx, red);
    float e[4], s = 0.f;
#pragma unroll
    for (int j = 0; j < 4; ++j) { e[j] = expf(l[j] - mx); s += e[j]; }
    s = bred_sum(s, red);
    const float inv = 1.f / s;
    float4 o;
    o.x = e[0] * inv; o.y = e[1] * inv; o.z = e[2] * inv; o.w = e[3] * inv;
    *(float4*)(posS + (long)n * NN_ + tid * 4) = o;
}

// ---------------- generic fp32 tiled GEMM (unchanged) ----------------
template <int BM, int BN, int TM, int TN, bool TRANS_B, bool SCALE_K>
__global__ __launch_bounds__(256) void gemm_kernel(
    const float* __restrict__ A, const float* __restrict__ B,
    float* __restrict__ C, const float* __restrict__ scaleK,
    int M, int N, int K,
    long sA1, long sA2, int divA, long sB1, int divB, long sC, float alpha) {
    constexpr int BKc = 8;
    const int z = blockIdx.z;
    A += (long)(z / divA) * sA1 + (long)(z % divA) * sA2;
    B += (long)(z / divB) * sB1;
    C += (long)z * sC;

    __shared__ float As[BKc][BM + 4];
    __shared__ float Bs[BKc][BN + 4];

    const int tid = threadIdx.x;
    const int bm = blockIdx.y * BM;
    const int bn = blockIdx.x * BN;
    constexpr int TX = BN / TN;
    const int tx = tid % TX;
    const int ty = tid / TX;

    float acc[TM][TN];
#pragma unroll
    for (int i = 0; i < TM; ++i)
#pragma unroll
        for (int j = 0; j < TN; ++j) acc[i][j] = 0.f;

    for (int k0 = 0; k0 < K; k0 += BKc) {
        {
            const int m = tid >> 1;
            const int kg = (tid & 1) * 4;
            float4 v = *(const float4*)(A + (long)(bm + m) * K + (k0 + kg));
            if (SCALE_K) {
                v.x *= fabsf(scaleK[k0 + kg + 0]);
                v.y *= fabsf(scaleK[k0 + kg + 1]);
                v.z *= fabsf(scaleK[k0 + kg + 2]);
                v.w *= fabsf(scaleK[k0 + kg + 3]);
            }
            As[kg + 0][m] = v.x; As[kg + 1][m] = v.y;
            As[kg + 2][m] = v.z; As[kg + 3][m] = v.w;
        }
        if (TRANS_B) {
            if (BN == 128 || tid < BN * 2) {
                const int n = tid >> 1;
                const int kg = (tid & 1) * 4;
                float4 v = *(const float4*)(B + (long)(bn + n) * K + (k0 + kg));
                Bs[kg + 0][n] = v.x; Bs[kg + 1][n] = v.y;
                Bs[kg + 2][n] = v.z; Bs[kg + 3][n] = v.w;
            }
        } else {
            if (BN == 128 || tid < BN * 2) {
                const int kk = tid / (BN / 4);
                const int n4 = (tid % (BN / 4)) * 4;
                float4 v = *(const float4*)(B + (long)(k0 + kk) * N + bn + n4);
                *(float4*)&Bs[kk][n4] = v;
            }
        }
        __syncthreads();
#pragma unroll
        for (int kk = 0; kk < BKc; ++kk) {
            float a[TM], bb[TN];
#pragma unroll
            for (int i = 0; i < TM; ++i) {
                const int r = (TM == 8) ? ((i < 4) ? ty * 4 + i : BM / 2 + ty * 4 + (i - 4))
                                        : ty * TM + i;
                a[i] = As[kk][r];
            }
#pragma unroll
            for (int j = 0; j < TN; ++j) {
                const int c = (TN == 8) ? ((j < 4) ? tx * 4 + j : BN / 2 + tx * 4 + (j - 4))
                                        : tx * TN + j;
                bb[j] = Bs[kk][c];
            }
#pragma unroll
            for (int i = 0; i < TM; ++i)
#pragma unroll
                for (int j = 0; j < TN; ++j) acc[i][j] = fmaf(a[i], bb[j], acc[i][j]);
        }
        __syncthreads();
    }
#pragma unroll
    for (int i = 0; i < TM; ++i) {
        const int r = (TM == 8) ? ((i < 4) ? ty * 4 + i : BM / 2 + ty * 4 + (i - 4))
                                : ty * TM + i;
#pragma unroll
        for (int jg = 0; jg < TN / 4; ++jg) {
            const int c = (TN == 8) ? ((jg == 0) ? tx * 4 : BN / 2 + tx * 4) : tx * TN;
            float4 v;
            v.x = acc[i][jg * 4 + 0] * alpha;
            v.y = acc[i][jg * 4 + 1] * alpha;
            v.z = acc[i][jg * 4 + 2] * alpha;
            v.w = acc[i][jg * 4 + 3] * alpha;
            *(float4*)(C + (long)(bm + r) * N + bn + c) = v;
        }
    }
}

// ---------------- blend + entropy + route -> bf16 attn_sel ----------
__global__ __launch_bounds__(256) void blend_kernel(
    const float* __restrict__ S, const float* __restrict__ pos,
    const float* __restrict__ gating, const float* __restrict__ h_temp,
    float* __restrict__ heat, __bf16* __restrict__ Pb) {
    __shared__ float red[4];
    const int bn = blockIdx.x;
    const int b = bn >> 10, n = bn & 1023;
    const float* S0 = S + ((long)(b * 2 + 0) * NN_ + n) * NN_;
    const float* S1 = S + ((long)(b * 2 + 1) * NN_ + n) * NN_;
    const int tid = threadIdx.x;

    float4 l0 = *(const float4*)(S0 + tid * 4);
    float4 l1 = *(const float4*)(S1 + tid * 4);
    float4 pv = *(const float4*)(pos + (long)n * NN_ + tid * 4);

    float m0 = fmaxf(fmaxf(l0.x, l0.y), fmaxf(l0.z, l0.w));
    m0 = bred_max(m0, red);
    float e0x = expf(l0.x - m0), e0y = expf(l0.y - m0),
          e0z = expf(l0.z - m0), e0w = expf(l0.w - m0);
    float s0 = bred_sum(e0x + e0y + e0z + e0w, red);
    const float i0 = 1.f / s0;
    float m1 = fmaxf(fmaxf(l1.x, l1.y), fmaxf(l1.z, l1.w));
    m1 = bred_max(m1, red);
    float e1x = expf(l1.x - m1), e1y = expf(l1.y - m1),
          e1z = expf(l1.z - m1), e1w = expf(l1.w - m1);
    float s1 = bred_sum(e1x + e1y + e1z + e1w, red);
    const float i1 = 1.f / s1;

    const float g = 1.f / (1.f + expf(-gating[0]));
    const float cg = 1.f - g;

    float a0[4], a1[4];
    a0[0] = cg * (e0x * i0) + g * pv.x; a0[1] = cg * (e0y * i0) + g * pv.y;
    a0[2] = cg * (e0z * i0) + g * pv.z; a0[3] = cg * (e0w * i0) + g * pv.w;
    a1[0] = cg * (e1x * i1) + g * pv.x; a1[1] = cg * (e1y * i1) + g * pv.y;
    a1[2] = cg * (e1z * i1) + g * pv.z; a1[3] = cg * (e1w * i1) + g * pv.w;

    float ent0 = 0.f, ent1 = 0.f;
#pragma unroll
    for (int j = 0; j < 4; ++j) {
        ent0 -= a0[j] * logf(a0[j] + 1e-8f);
        ent1 -= a1[j] * logf(a1[j] + 1e-8f);
    }
    ent0 = bred_sum(ent0, red);
    ent1 = bred_sum(ent1, red);

    const float ht = h_temp[0];
    const float hm0 = 2.f - 2.f / (1.f + expf(-ht * ent0));
    const float hm1 = 2.f - 2.f / (1.f + expf(-ht * ent1));
    const bool fg = (hm0 >= hm1);
    if (tid == 0) heat[bn] = fg ? hm0 : hm1;

    bf16x4 o;
    o[0] = (__bf16)(fg ? a0[0] : a1[0]);
    o[1] = (__bf16)(fg ? a0[1] : a1[1]);
    o[2] = (__bf16)(fg ? a0[2] : a1[2]);
    o[3] = (__bf16)(fg ? a0[3] : a1[3]);
    *(bf16x4*)(Pb + ((long)b * NN_ + n) * NN_ + tid * 4) = o;
}

// ---------------- y -> bf16 transposed: yt[b][d][m] ----------------
__global__ __launch_bounds__(256) void transpose_y(
    const float* __restrict__ y, __bf16* __restrict__ yt) {
    __shared__ __bf16 t[64][72];
    const int b = blockIdx.z;
    const int m0 = blockIdx.x * 64, d0 = blockIdx.y * 64;
    const int tid = threadIdx.x;
    const int c = tid & 15;
    const int r = tid >> 4;
#pragma unroll
    for (int p = 0; p < 4; ++p) {
        const int row = r + p * 16;
        float4 v = *(const float4*)(y + ((long)b * NN_ + m0 + row) * ND + d0 + c * 4);
        t[c * 4 + 0][row] = (__bf16)v.x;
        t[c * 4 + 1][row] = (__bf16)v.y;
        t[c * 4 + 2][row] = (__bf16)v.z;
        t[c * 4 + 3][row] = (__bf16)v.w;
    }
    __syncthreads();
#pragma unroll
    for (int p = 0; p < 4; ++p) {
        const int d = r + p * 16;
        bf16x4 o;
        o[0] = t[d][c * 4 + 0]; o[1] = t[d][c * 4 + 1];
        o[2] = t[d][c * 4 + 2]; o[3] = t[d][c * 4 + 3];
        *(bf16x4*)(yt + ((long)b * ND + d0 + d) * NN_ + m0 + c * 4) = o;
    }
}

// ---------------- out = P @ y via bf16 MFMA (no LDS, L2-resident) ---------
// P: [B][1024][1024] bf16 row-major; Yt: [B][256][1024] bf16 (y transposed).
// Block: 256 thr = 4 waves (2x2); wave computes 32x32; grid (4,16,8)=512.
__global__ __launch_bounds__(256) void out_mfma(
    const __bf16* __restrict__ P, const __bf16* __restrict__ Yt,
    float* __restrict__ out) {
    const int b = blockIdx.z;
    const int m0 = blockIdx.y * 64;
    const int n0 = blockIdx.x * 64;
    const int tid = threadIdx.x;
    const int wave = tid >> 6;
    const int lane = tid & 63;
    const int wm = wave >> 1, wn = wave & 1;
    const int quad = lane >> 4, l16 = lane & 15;

    const __bf16* Pbase = P + (long)b * NN_ * NN_;
    const __bf16* Ybase = Yt + (long)b * ND * NN_;

    f32x4 acc[2][2] = {{{0.f, 0.f, 0.f, 0.f}, {0.f, 0.f, 0.f, 0.f}},
                       {{0.f, 0.f, 0.f, 0.f}, {0.f, 0.f, 0.f, 0.f}}};
    const int rowA = m0 + wm * 32 + l16;   // + mi*16
    const int rowB = n0 + wn * 32 + l16;   // + ni*16
    const int kbase = quad * 8;

    for (int k0 = 0; k0 < NN_; k0 += 64) {
#pragma unroll
        for (int kk = 0; kk < 2; ++kk) {
            const int k = k0 + kk * 32 + kbase;
            bf16x8 a0 = *(const bf16x8*)(Pbase + (long)(rowA)*NN_ + k);
            bf16x8 a1 = *(const bf16x8*)(Pbase + (long)(rowA + 16) * NN_ + k);
            bf16x8 b0 = *(const bf16x8*)(Ybase + (long)(rowB)*NN_ + k);
            bf16x8 b1 = *(const bf16x8*)(Ybase + (long)(rowB + 16) * NN_ + k);
            acc[0][0] = __builtin_amdgcn_mfma_f32_16x16x32_bf16(a0, b0, acc[0][0], 0, 0, 0);
            acc[0][1] = __builtin_amdgcn_mfma_f32_16x16x32_bf16(a0, b1, acc[0][1], 0, 0, 0);
            acc[1][0] = __builtin_amdgcn_mfma_f32_16x16x32_bf16(a1, b0, acc[1][0], 0, 0, 0);
            acc[1][1] = __builtin_amdgcn_mfma_f32_16x16x32_bf16(a1, b1, acc[1][1], 0, 0, 0);
        }
    }
#pragma unroll
    for (int mi = 0; mi < 2; ++mi)
#pragma unroll
        for (int ni = 0; ni < 2; ++ni) {
            const int col = n0 + wn * 32 + ni * 16 + l16;
            float* op = out + ((long)b * NN_ + (m0 + wm * 32 + mi * 16 + quad * 4)) * ND + col;
#pragma unroll
            for (int r = 0; r < 4; ++r) op[(long)r * ND] = acc[mi][ni][r];
        }
}

extern "C" void kernel_launch(void* const* d_in, const int* in_sizes, int n_in,
                              void* d_out, int out_size, void* d_ws, size_t ws_size,
                              hipStream_t stream) {
    const float* x      = (const float*)d_in[0];
    const float* y      = (const float*)d_in[1];
    const float* coords = (const float*)d_in[2];
    const float* U      = (const float*)d_in[3];
    const float* S1p    = (const float*)d_in[4];
    const float* S2p    = (const float*)d_in[5];
    const float* gating = (const float*)d_in[6];
    const float* h_temp = (const float*)d_in[7];
    const float* p_temp = (const float*)d_in[8];
    const float* pos_emb= (const float*)d_in[9];

    float* out  = (float*)d_out;
    float* heat = out + (long)NB * NN_ * ND;

    float* ws  = (float*)d_ws;
    float* pos = ws;                        // 1M f
    float* t   = pos + NN_ * NN_;           // 2M f
    float* xs  = t + NB * NN_ * ND;         // 4M f
    float* S   = xs + 2L * NB * NN_ * ND;   // 16M f
    __bf16* yt = (__bf16*)(S + 16L * 1024 * 1024);  // 2M bf16 (4 MB)
    __bf16* Pb = yt + (long)NB * ND * NN_;          // 8M bf16 (16 MB)

    const long ND2 = (long)NN_ * ND;
    const long BND = (long)NB * NN_ * ND;

    pos_kernel<<<dim3(NN_), dim3(256), 0, stream>>>(coords, pos_emb, p_temp, pos);

    transpose_y<<<dim3(NN_ / 64, ND / 64, NB), 256, 0, stream>>>(y, yt);

    gemm_kernel<128, 64, 8, 4, true, false><<<dim3(ND / 64, (NB * NN_) / 128, 1), 256, 0, stream>>>(
        x, U, t, nullptr, NB * NN_, ND, ND, 0, 0, 1, 0, 1, 0, 1.0f);

    gemm_kernel<128, 64, 8, 4, false, true><<<dim3(ND / 64, (NB * NN_) / 128, 1), 256, 0, stream>>>(
        t, U, xs, S1p, NB * NN_, ND, ND, 0, 0, 1, 0, 1, 0, 1.0f);
    gemm_kernel<128, 64, 8, 4, false, true><<<dim3(ND / 64, (NB * NN_) / 128, 1), 256, 0, stream>>>(
        t, U, xs + BND, S2p, NB * NN_, ND, ND, 0, 0, 1, 0, 1, 0, 1.0f);

    gemm_kernel<128, 128, 8, 8, true, false><<<dim3(NN_ / 128, NN_ / 128, NB * 2), 256, 0, stream>>>(
        xs, y, S, nullptr, NN_, NN_, ND,
        ND2, BND, 2, ND2, 2, (long)NN_ * NN_, 0.0625f);

    blend_kernel<<<dim3(NB * NN_), dim3(256), 0, stream>>>(S, pos, gating, h_temp, heat, Pb);

    out_mfma<<<dim3(ND / 64, NN_ / 64, NB), 256, 0, stream>>>(Pb, yt, out);

    (void)in_sizes; (void)n_in; (void)out_size; (void)ws_size;
}

// Round 3
// 224.238 us; speedup vs baseline: 2.0020x; 1.5930x over previous
//
#include <hip/hip_runtime.h>
#include <hip/hip_bf16.h>

// B=8, N=1024, D=256, fp32 in/out.
// R3: all GEMMs on MFMA. Spectral chain + scores use split-bf16 (hi/lo) x3
// emulation for fp32-equivalent accuracy (protects the discrete entropy route);
// out GEMM stays single-bf16 (post-routing, quantization already validated).

#define NB 8
#define NN_ 1024
#define ND 256

typedef __bf16 bf16x8 __attribute__((ext_vector_type(8)));
typedef __bf16 bf16x4 __attribute__((ext_vector_type(4)));
typedef float f32x4 __attribute__((ext_vector_type(4)));

// ---------------- reductions ----------------
__device__ inline float wred_sum(float v) {
#pragma unroll
    for (int o = 32; o; o >>= 1) v += __shfl_xor(v, o, 64);
    return v;
}
__device__ inline float wred_max(float v) {
#pragma unroll
    for (int o = 32; o; o >>= 1) v = fmaxf(v, __shfl_xor(v, o, 64));
    return v;
}
__device__ inline float bred_sum(float v, float* red) {
    v = wred_sum(v);
    int w = threadIdx.x >> 6;
    __syncthreads();
    if ((threadIdx.x & 63) == 0) red[w] = v;
    __syncthreads();
    return red[0] + red[1] + red[2] + red[3];
}
__device__ inline float bred_max(float v, float* red) {
    v = wred_max(v);
    int w = threadIdx.x >> 6;
    __syncthreads();
    if ((threadIdx.x & 63) == 0) red[w] = v;
    __syncthreads();
    return fmaxf(fmaxf(red[0], red[1]), fmaxf(red[2], red[3]));
}

// ---------------- pos softmax ----------------
__global__ __launch_bounds__(256) void pos_kernel(
    const float* __restrict__ coords, const float* __restrict__ pos_emb,
    const float* __restrict__ p_temp, float* __restrict__ posS) {
    __shared__ float red[4];
    const int n = blockIdx.x;
    const int tid = threadIdx.x;
    const float pt = -fabsf(p_temp[0]);
    float pe[6];
#pragma unroll
    for (int c = 0; c < 6; ++c) pe[c] = pos_emb[n * 6 + c];
    const float* cr = coords + (long)n * NN_ * 6;
    float l[4];
#pragma unroll
    for (int j = 0; j < 4; ++j) {
        const int m = tid * 4 + j;
        const float* cp = cr + m * 6;
        float d = 0.f;
#pragma unroll
        for (int c = 0; c < 6; ++c) d += cp[c] * pe[c];
        l[j] = pt * d;
    }
    float mx = fmaxf(fmaxf(l[0], l[1]), fmaxf(l[2], l[3]));
    mx = bred_max(mx, red);
    float e[4], s = 0.f;
#pragma unroll
    for (int j = 0; j < 4; ++j) { e[j] = expf(l[j] - mx); s += e[j]; }
    s = bred_sum(s, red);
    const float inv = 1.f / s;
    float4 o;
    o.x = e[0] * inv; o.y = e[1] * inv; o.z = e[2] * inv; o.w = e[3] * inv;
    *(float4*)(posS + (long)n * NN_ + tid * 4) = o;
}

// ---------------- fp32 -> bf16 hi/lo split ----------------
__global__ __launch_bounds__(256) void conv_split(
    const float* __restrict__ src, __bf16* __restrict__ hi,
    __bf16* __restrict__ lo, int n4) {
    int i = blockIdx.x * 256 + threadIdx.x;
    const int stride = gridDim.x * 256;
    for (; i < n4; i += stride) {
        float4 v = ((const float4*)src)[i];
        bf16x4 h, l;
        h[0] = (__bf16)v.x; l[0] = (__bf16)(v.x - (float)h[0]);
        h[1] = (__bf16)v.y; l[1] = (__bf16)(v.y - (float)h[1]);
        h[2] = (__bf16)v.z; l[2] = (__bf16)(v.z - (float)h[2]);
        h[3] = (__bf16)v.w; l[3] = (__bf16)(v.w - (float)h[3]);
        ((bf16x4*)hi)[i] = h;
        ((bf16x4*)lo)[i] = l;
    }
}

// ---------------- U prep: split U; build Wt_k[n][c] = |S_k[c]|*U[c][n] -------
__global__ __launch_bounds__(256) void conv_U(
    const float* __restrict__ U, const float* __restrict__ S1,
    const float* __restrict__ S2, __bf16* __restrict__ Uh, __bf16* __restrict__ Ul,
    __bf16* __restrict__ Wh, __bf16* __restrict__ Wl) {
    const int n = blockIdx.x, k = threadIdx.x;
    float u = U[n * ND + k];
    __bf16 h = (__bf16)u;
    Uh[n * ND + k] = h; Ul[n * ND + k] = (__bf16)(u - (float)h);
    float ukn = U[k * ND + n];
    float w1 = ukn * fabsf(S1[k]);
    float w2 = ukn * fabsf(S2[k]);
    __bf16 h1 = (__bf16)w1, h2 = (__bf16)w2;
    Wh[n * ND + k] = h1;             Wl[n * ND + k] = (__bf16)(w1 - (float)h1);
    Wh[65536 + n * ND + k] = h2;     Wl[65536 + n * ND + k] = (__bf16)(w2 - (float)h2);
}

// ---------------- y: emit yt (bf16 transposed) + y hi/lo split --------------
__global__ __launch_bounds__(256) void prep_y(
    const float* __restrict__ y, __bf16* __restrict__ yt,
    __bf16* __restrict__ Yh, __bf16* __restrict__ Yl) {
    __shared__ __bf16 t[64][72];
    const int b = blockIdx.z;
    const int m0 = blockIdx.x * 64, d0 = blockIdx.y * 64;
    const int tid = threadIdx.x;
    const int c = tid & 15;
    const int r = tid >> 4;
#pragma unroll
    for (int p = 0; p < 4; ++p) {
        const int row = r + p * 16;
        const long gi = ((long)b * NN_ + m0 + row) * ND + d0 + c * 4;
        float4 v = *(const float4*)(y + gi);
        bf16x4 h, l;
        h[0] = (__bf16)v.x; l[0] = (__bf16)(v.x - (float)h[0]);
        h[1] = (__bf16)v.y; l[1] = (__bf16)(v.y - (float)h[1]);
        h[2] = (__bf16)v.z; l[2] = (__bf16)(v.z - (float)h[2]);
        h[3] = (__bf16)v.w; l[3] = (__bf16)(v.w - (float)h[3]);
        *(bf16x4*)(Yh + gi) = h;
        *(bf16x4*)(Yl + gi) = l;
        t[c * 4 + 0][row] = h[0]; t[c * 4 + 1][row] = h[1];
        t[c * 4 + 2][row] = h[2]; t[c * 4 + 3][row] = h[3];
    }
    __syncthreads();
#pragma unroll
    for (int p = 0; p < 4; ++p) {
        const int d = r + p * 16;
        bf16x4 o;
        o[0] = t[d][c * 4 + 0]; o[1] = t[d][c * 4 + 1];
        o[2] = t[d][c * 4 + 2]; o[3] = t[d][c * 4 + 3];
        *(bf16x4*)(yt + ((long)b * ND + d0 + d) * NN_ + m0 + c * 4) = o;
    }
}

// ---------------- MFMA GEMM (NT), optional split-bf16 x3 --------------------
template <int BN, bool SPLIT, int OUTM>
__global__ __launch_bounds__(256) void mgemm(
    const __bf16* __restrict__ Ah, const __bf16* __restrict__ Al,
    const __bf16* __restrict__ Bh, const __bf16* __restrict__ Bl,
    float* __restrict__ C, __bf16* __restrict__ Ch, __bf16* __restrict__ Cl,
    int M, int N, int K,
    long sA1, long sA2, int divA, long sB1, int divB, long sC, float alpha) {
    constexpr int BM = 128, BK = 32, RS = 40;  // +8 pad: 2-way LDS aliasing (free)
    constexpr int NBUF = SPLIT ? 2 : 1;
    constexpr int NF = BN / 32;  // n-frags per wave (wave tile 64 x BN/2)
    __shared__ __bf16 As[NBUF][BM * RS];
    __shared__ __bf16 Bs[NBUF][BN * RS];

    const int z = blockIdx.z;
    const long aoff = (long)(z / divA) * sA1 + (long)(z % divA) * sA2;
    const long boff = (long)(z / divB) * sB1;
    Ah += aoff; if (SPLIT) Al += aoff;
    Bh += boff; if (SPLIT) Bl += boff;

    const int tid = threadIdx.x;
    const int bm = blockIdx.y * BM, bn = blockIdx.x * BN;
    const int wave = tid >> 6, lane = tid & 63;
    const int wm = wave >> 1, wn = wave & 1;
    const int quad = lane >> 4, l16 = lane & 15;

    f32x4 acc[4][NF];
#pragma unroll
    for (int i = 0; i < 4; ++i)
#pragma unroll
        for (int j = 0; j < NF; ++j) acc[i][j] = (f32x4){0.f, 0.f, 0.f, 0.f};

    const int arow = tid >> 1, ak = (tid & 1) * 16;

    for (int k0 = 0; k0 < K; k0 += BK) {
        {   // stage A: 128 x 32
            const long g = (long)(bm + arow) * K + k0 + ak;
            *(bf16x8*)&As[0][arow * RS + ak] = *(const bf16x8*)(Ah + g);
            *(bf16x8*)&As[0][arow * RS + ak + 8] = *(const bf16x8*)(Ah + g + 8);
            if (SPLIT) {
                *(bf16x8*)&As[1][arow * RS + ak] = *(const bf16x8*)(Al + g);
                *(bf16x8*)&As[1][arow * RS + ak + 8] = *(const bf16x8*)(Al + g + 8);
            }
        }
        if (BN == 128) {
            const long g = (long)(bn + arow) * K + k0 + ak;
            *(bf16x8*)&Bs[0][arow * RS + ak] = *(const bf16x8*)(Bh + g);
            *(bf16x8*)&Bs[0][arow * RS + ak + 8] = *(const bf16x8*)(Bh + g + 8);
            if (SPLIT) {
                *(bf16x8*)&Bs[1][arow * RS + ak] = *(const bf16x8*)(Bl + g);
                *(bf16x8*)&Bs[1][arow * RS + ak + 8] = *(const bf16x8*)(Bl + g + 8);
            }
        } else {  // BN == 64
            const int brow = tid >> 2, bk = (tid & 3) * 8;
            const long g = (long)(bn + brow) * K + k0 + bk;
            *(bf16x8*)&Bs[0][brow * RS + bk] = *(const bf16x8*)(Bh + g);
            if (SPLIT)
                *(bf16x8*)&Bs[1][brow * RS + bk] = *(const bf16x8*)(Bl + g);
        }
        __syncthreads();

        bf16x8 a_h[4], a_l[4], b_h[NF], b_l[NF];
#pragma unroll
        for (int mi = 0; mi < 4; ++mi) {
            const int r = (wm * 64 + mi * 16 + l16) * RS + quad * 8;
            a_h[mi] = *(const bf16x8*)&As[0][r];
            if (SPLIT) a_l[mi] = *(const bf16x8*)&As[1][r];
        }
#pragma unroll
        for (int ni = 0; ni < NF; ++ni) {
            const int r = (wn * (BN / 2) + ni * 16 + l16) * RS + quad * 8;
            b_h[ni] = *(const bf16x8*)&Bs[0][r];
            if (SPLIT) b_l[ni] = *(const bf16x8*)&Bs[1][r];
        }
#pragma unroll
        for (int mi = 0; mi < 4; ++mi)
#pragma unroll
            for (int ni = 0; ni < NF; ++ni) {
                acc[mi][ni] = __builtin_amdgcn_mfma_f32_16x16x32_bf16(
                    a_h[mi], b_h[ni], acc[mi][ni], 0, 0, 0);
                if (SPLIT) {
                    acc[mi][ni] = __builtin_amdgcn_mfma_f32_16x16x32_bf16(
                        a_h[mi], b_l[ni], acc[mi][ni], 0, 0, 0);
                    acc[mi][ni] = __builtin_amdgcn_mfma_f32_16x16x32_bf16(
                        a_l[mi], b_h[ni], acc[mi][ni], 0, 0, 0);
                }
            }
        __syncthreads();
    }

    C += (long)z * sC; Ch += (long)z * sC; Cl += (long)z * sC;
#pragma unroll
    for (int mi = 0; mi < 4; ++mi) {
        const int row0 = bm + wm * 64 + mi * 16 + quad * 4;
#pragma unroll
        for (int ni = 0; ni < NF; ++ni) {
            const int col = bn + wn * (BN / 2) + ni * 16 + l16;
#pragma unroll
            for (int r = 0; r < 4; ++r) {
                const float v = acc[mi][ni][r] * alpha;
                const long idx = (long)(row0 + r) * N + col;
                if (OUTM == 0) {
                    C[idx] = v;
                } else {
                    const __bf16 h = (__bf16)v;
                    Ch[idx] = h;
                    Cl[idx] = (__bf16)(v - (float)h);
                }
            }
        }
    }
}

// ---------------- blend + entropy + route -> bf16 attn_sel ------------------
__global__ __launch_bounds__(256) void blend_kernel(
    const float* __restrict__ S, const float* __restrict__ pos,
    const float* __restrict__ gating, const float* __restrict__ h_temp,
    float* __restrict__ heat, __bf16* __restrict__ Pb) {
    __shared__ float red[4];
    const int bn = blockIdx.x;
    const int b = bn >> 10, n = bn & 1023;
    const float* S0 = S + ((long)(b * 2 + 0) * NN_ + n) * NN_;
    const float* S1 = S + ((long)(b * 2 + 1) * NN_ + n) * NN_;
    const int tid = threadIdx.x;

    float4 l0 = *(const float4*)(S0 + tid * 4);
    float4 l1 = *(const float4*)(S1 + tid * 4);
    float4 pv = *(const float4*)(pos + (long)n * NN_ + tid * 4);

    float m0 = fmaxf(fmaxf(l0.x, l0.y), fmaxf(l0.z, l0.w));
    m0 = bred_max(m0, red);
    float e0x = expf(l0.x - m0), e0y = expf(l0.y - m0),
          e0z = expf(l0.z - m0), e0w = expf(l0.w - m0);
    float s0 = bred_sum(e0x + e0y + e0z + e0w, red);
    const float i0 = 1.f / s0;
    float m1 = fmaxf(fmaxf(l1.x, l1.y), fmaxf(l1.z, l1.w));
    m1 = bred_max(m1, red);
    float e1x = expf(l1.x - m1), e1y = expf(l1.y - m1),
          e1z = expf(l1.z - m1), e1w = expf(l1.w - m1);
    float s1 = bred_sum(e1x + e1y + e1z + e1w, red);
    const float i1 = 1.f / s1;

    const float g = 1.f / (1.f + expf(-gating[0]));
    const float cg = 1.f - g;

    float a0[4], a1[4];
    a0[0] = cg * (e0x * i0) + g * pv.x; a0[1] = cg * (e0y * i0) + g * pv.y;
    a0[2] = cg * (e0z * i0) + g * pv.z; a0[3] = cg * (e0w * i0) + g * pv.w;
    a1[0] = cg * (e1x * i1) + g * pv.x; a1[1] = cg * (e1y * i1) + g * pv.y;
    a1[2] = cg * (e1z * i1) + g * pv.z; a1[3] = cg * (e1w * i1) + g * pv.w;

    float ent0 = 0.f, ent1 = 0.f;
#pragma unroll
    for (int j = 0; j < 4; ++j) {
        ent0 -= a0[j] * logf(a0[j] + 1e-8f);
        ent1 -= a1[j] * logf(a1[j] + 1e-8f);
    }
    ent0 = bred_sum(ent0, red);
    ent1 = bred_sum(ent1, red);

    const float ht = h_temp[0];
    const float hm0 = 2.f - 2.f / (1.f + expf(-ht * ent0));
    const float hm1 = 2.f - 2.f / (1.f + expf(-ht * ent1));
    const bool fg = (hm0 >= hm1);
    if (tid == 0) heat[bn] = fg ? hm0 : hm1;

    bf16x4 o;
    o[0] = (__bf16)(fg ? a0[0] : a1[0]);
    o[1] = (__bf16)(fg ? a0[1] : a1[1]);
    o[2] = (__bf16)(fg ? a0[2] : a1[2]);
    o[3] = (__bf16)(fg ? a0[3] : a1[3]);
    *(bf16x4*)(Pb + ((long)b * NN_ + n) * NN_ + tid * 4) = o;
}

extern "C" void kernel_launch(void* const* d_in, const int* in_sizes, int n_in,
                              void* d_out, int out_size, void* d_ws, size_t ws_size,
                              hipStream_t stream) {
    const float* x      = (const float*)d_in[0];
    const float* y      = (const float*)d_in[1];
    const float* coords = (const float*)d_in[2];
    const float* U      = (const float*)d_in[3];
    const float* S1p    = (const float*)d_in[4];
    const float* S2p    = (const float*)d_in[5];
    const float* gating = (const float*)d_in[6];
    const float* h_temp = (const float*)d_in[7];
    const float* p_temp = (const float*)d_in[8];
    const float* pos_emb= (const float*)d_in[9];

    float* out  = (float*)d_out;
    float* heat = out + (long)NB * NN_ * ND;

    // workspace layout (sequential region reuse; ~105.5 MB total)
    char* ws = (char*)d_ws;
    const long MB = 1 << 20;
    float*  Sf  = (float*)(ws);              // [0,64M)   scores fp32
    float*  pos = (float*)(ws + 64 * MB);    // [64,68M)
    // [68,84M): phase1 Xh/Xl -> phase2 XSh/XSl -> phase3 Pb (lifetimes disjoint)
    __bf16* Xh  = (__bf16*)(ws + 68 * MB);
    __bf16* Xl  = (__bf16*)(ws + 72 * MB);
    __bf16* XSh = (__bf16*)(ws + 68 * MB);   // [2][8192][256]
    __bf16* XSl = (__bf16*)(ws + 76 * MB);
    __bf16* Pb  = (__bf16*)(ws + 68 * MB);   // [8][1024][1024]
    __bf16* yt  = (__bf16*)(ws + 84 * MB);   // [8][256][1024]
    __bf16* Yh  = (__bf16*)(ws + 88 * MB);
    __bf16* Yl  = (__bf16*)(ws + 92 * MB);
    __bf16* Th  = (__bf16*)(ws + 96 * MB);
    __bf16* Tl  = (__bf16*)(ws + 100 * MB);
    __bf16* Uh  = (__bf16*)(ws + 104 * MB);
    __bf16* Ul  = Uh + 65536;
    __bf16* Wh  = Uh + 2 * 65536;            // [2][256][256]
    __bf16* Wl  = Uh + 4 * 65536;

    const long ND2 = (long)NN_ * ND;   // 262144
    const long BND = (long)NB * ND2;   // 2097152

    pos_kernel<<<dim3(NN_), 256, 0, stream>>>(coords, pos_emb, p_temp, pos);
    conv_split<<<dim3(2048), 256, 0, stream>>>(x, Xh, Xl, (int)(BND / 4));
    prep_y<<<dim3(16, 4, NB), 256, 0, stream>>>(y, yt, Yh, Yl);
    conv_U<<<dim3(ND), ND, 0, stream>>>(U, S1p, S2p, Uh, Ul, Wh, Wl);

    // t = x @ U^T  (split in, split out)   M=8192, N=256, K=256
    mgemm<64, true, 1><<<dim3(4, 64, 1), 256, 0, stream>>>(
        Xh, Xl, Uh, Ul, nullptr, Th, Tl, NB * NN_, ND, ND,
        0, 0, 1, 0, 1, 0, 1.0f);

    // xs_k = t @ W_k  (z=k) -> XS [2][8192][256]
    mgemm<64, true, 1><<<dim3(4, 64, 2), 256, 0, stream>>>(
        Th, Tl, Wh, Wl, nullptr, XSh, XSl, NB * NN_, ND, ND,
        0, 0, 1, 65536, 1, BND, 1.0f);

    // scores: S[b][k] = (xs_k[b] @ y[b]^T) * D^-0.5 ; z = b*2+k
    mgemm<128, true, 0><<<dim3(8, 8, NB * 2), 256, 0, stream>>>(
        XSh, XSl, Yh, Yl, Sf, nullptr, nullptr, NN_, NN_, ND,
        ND2, BND, 2, ND2, 2, (long)NN_ * NN_, 0.0625f);

    // blend + entropy + route -> Pb (bf16), heat
    blend_kernel<<<dim3(NB * NN_), 256, 0, stream>>>(Sf, pos, gating, h_temp, heat, Pb);

    // out[b] = Pb[b] @ yt[b]^T   M=1024, N=256, K=1024
    mgemm<64, false, 0><<<dim3(4, 8, NB), 256, 0, stream>>>(
        Pb, nullptr, yt, nullptr, out, nullptr, nullptr, NN_, ND, NN_,
        (long)NN_ * NN_, 0, 1, ND2, 1, ND2, 1.0f);

    (void)in_sizes; (void)n_in; (void)out_size; (void)ws_size;
}

// Round 4
// 220.532 us; speedup vs baseline: 2.0357x; 1.0168x over previous
//
#include <hip/hip_runtime.h>
#include <hip/hip_bf16.h>
#include <stdint.h>

// B=8, N=1024, D=256, fp32 in/out.
// R4: mgemm staged via global_load_lds (16B DMA, XOR-swizzled source so frag
// reads are 2-way max); t-GEMM folded into M_k = U^T diag|S_k| U (built on
// device, fp32); pos_kernel coalescing fixed.

#define NB 8
#define NN_ 1024
#define ND 256

typedef __bf16 bf16x8 __attribute__((ext_vector_type(8)));
typedef __bf16 bf16x4 __attribute__((ext_vector_type(4)));
typedef float f32x4 __attribute__((ext_vector_type(4)));

// ---------------- async global->LDS (16B per lane, wave-uniform LDS base) ---
__device__ inline void gl_lds(const __bf16* g, __bf16* l) {
    auto gp = (const __attribute__((address_space(1))) uint32_t*)(uintptr_t)g;
    auto lp = (__attribute__((address_space(3))) uint32_t*)(uintptr_t)l;
    __builtin_amdgcn_global_load_lds(gp, lp, 16, 0, 0);
}

// ---------------- reductions ----------------
__device__ inline float wred_sum(float v) {
#pragma unroll
    for (int o = 32; o; o >>= 1) v += __shfl_xor(v, o, 64);
    return v;
}
__device__ inline float wred_max(float v) {
#pragma unroll
    for (int o = 32; o; o >>= 1) v = fmaxf(v, __shfl_xor(v, o, 64));
    return v;
}
__device__ inline float bred_sum(float v, float* red) {
    v = wred_sum(v);
    int w = threadIdx.x >> 6;
    __syncthreads();
    if ((threadIdx.x & 63) == 0) red[w] = v;
    __syncthreads();
    return red[0] + red[1] + red[2] + red[3];
}
__device__ inline float bred_max(float v, float* red) {
    v = wred_max(v);
    int w = threadIdx.x >> 6;
    __syncthreads();
    if ((threadIdx.x & 63) == 0) red[w] = v;
    __syncthreads();
    return fmaxf(fmaxf(red[0], red[1]), fmaxf(red[2], red[3]));
}

// ---------------- pos softmax (coalesced: m = j*256+tid, float2 loads) ------
__global__ __launch_bounds__(256) void pos_kernel(
    const float* __restrict__ coords, const float* __restrict__ pos_emb,
    const float* __restrict__ p_temp, float* __restrict__ posS) {
    __shared__ float red[4];
    const int n = blockIdx.x;
    const int tid = threadIdx.x;
    const float pt = -fabsf(p_temp[0]);
    float pe[6];
#pragma unroll
    for (int c = 0; c < 6; ++c) pe[c] = pos_emb[n * 6 + c];
    const float* cr = coords + (long)n * NN_ * 6;
    float l[4];
#pragma unroll
    for (int j = 0; j < 4; ++j) {
        const int m = j * 256 + tid;
        const float2* cp = (const float2*)(cr + (long)m * 6);
        float2 c0 = cp[0], c1 = cp[1], c2 = cp[2];
        l[j] = pt * (c0.x * pe[0] + c0.y * pe[1] + c1.x * pe[2] +
                     c1.y * pe[3] + c2.x * pe[4] + c2.y * pe[5]);
    }
    float mx = fmaxf(fmaxf(l[0], l[1]), fmaxf(l[2], l[3]));
    mx = bred_max(mx, red);
    float e[4], s = 0.f;
#pragma unroll
    for (int j = 0; j < 4; ++j) { e[j] = expf(l[j] - mx); s += e[j]; }
    s = bred_sum(s, red);
    const float inv = 1.f / s;
#pragma unroll
    for (int j = 0; j < 4; ++j) posS[(long)n * NN_ + j * 256 + tid] = e[j] * inv;
}

// ---------------- fp32 -> bf16 hi/lo split ----------------
__global__ __launch_bounds__(256) void conv_split(
    const float* __restrict__ src, __bf16* __restrict__ hi,
    __bf16* __restrict__ lo, int n4) {
    int i = blockIdx.x * 256 + threadIdx.x;
    const int stride = gridDim.x * 256;
    for (; i < n4; i += stride) {
        float4 v = ((const float4*)src)[i];
        bf16x4 h, l;
        h[0] = (__bf16)v.x; l[0] = (__bf16)(v.x - (float)h[0]);
        h[1] = (__bf16)v.y; l[1] = (__bf16)(v.y - (float)h[1]);
        h[2] = (__bf16)v.z; l[2] = (__bf16)(v.z - (float)h[2]);
        h[3] = (__bf16)v.w; l[3] = (__bf16)(v.w - (float)h[3]);
        ((bf16x4*)hi)[i] = h;
        ((bf16x4*)lo)[i] = l;
    }
}

// ---------------- M_k = U^T diag(|S_k|) U  (symmetric), split hi/lo ---------
__global__ __launch_bounds__(256) void build_M(
    const float* __restrict__ U, const float* __restrict__ S1,
    const float* __restrict__ S2, __bf16* __restrict__ Mh,
    __bf16* __restrict__ Ml) {
    const int n = blockIdx.x, j = threadIdx.x;
    float a1 = 0.f, a2 = 0.f;
    for (int c = 0; c < ND; ++c) {
        const float un = U[c * ND + n];
        const float uj = U[c * ND + j];
        a1 = fmaf(fabsf(S1[c]) * un, uj, a1);
        a2 = fmaf(fabsf(S2[c]) * un, uj, a2);
    }
    const __bf16 h1 = (__bf16)a1, h2 = (__bf16)a2;
    Mh[n * ND + j] = h1;            Ml[n * ND + j] = (__bf16)(a1 - (float)h1);
    Mh[65536 + n * ND + j] = h2;    Ml[65536 + n * ND + j] = (__bf16)(a2 - (float)h2);
}

// ---------------- y: emit yt (bf16 transposed) + y hi/lo split --------------
__global__ __launch_bounds__(256) void prep_y(
    const float* __restrict__ y, __bf16* __restrict__ yt,
    __bf16* __restrict__ Yh, __bf16* __restrict__ Yl) {
    __shared__ __bf16 t[64][72];
    const int b = blockIdx.z;
    const int m0 = blockIdx.x * 64, d0 = blockIdx.y * 64;
    const int tid = threadIdx.x;
    const int c = tid & 15;
    const int r = tid >> 4;
#pragma unroll
    for (int p = 0; p < 4; ++p) {
        const int row = r + p * 16;
        const long gi = ((long)b * NN_ + m0 + row) * ND + d0 + c * 4;
        float4 v = *(const float4*)(y + gi);
        bf16x4 h, l;
        h[0] = (__bf16)v.x; l[0] = (__bf16)(v.x - (float)h[0]);
        h[1] = (__bf16)v.y; l[1] = (__bf16)(v.y - (float)h[1]);
        h[2] = (__bf16)v.z; l[2] = (__bf16)(v.z - (float)h[2]);
        h[3] = (__bf16)v.w; l[3] = (__bf16)(v.w - (float)h[3]);
        *(bf16x4*)(Yh + gi) = h;
        *(bf16x4*)(Yl + gi) = l;
        t[c * 4 + 0][row] = h[0]; t[c * 4 + 1][row] = h[1];
        t[c * 4 + 2][row] = h[2]; t[c * 4 + 3][row] = h[3];
    }
    __syncthreads();
#pragma unroll
    for (int p = 0; p < 4; ++p) {
        const int d = r + p * 16;
        bf16x4 o;
        o[0] = t[d][c * 4 + 0]; o[1] = t[d][c * 4 + 1];
        o[2] = t[d][c * 4 + 2]; o[3] = t[d][c * 4 + 3];
        *(bf16x4*)(yt + ((long)b * ND + d0 + d) * NN_ + m0 + c * 4) = o;
    }
}

// ---------------- MFMA GEMM (NT), global_load_lds staged, XOR swizzle -------
// LDS layout: row-major, 32 el/row, chunk (8 el) stored at slot = chunk ^ ((row>>1)&3).
template <int BN, bool SPLIT, int OUTM>
__global__ __launch_bounds__(256) void mgemm(
    const __bf16* __restrict__ Ah, const __bf16* __restrict__ Al,
    const __bf16* __restrict__ Bh, const __bf16* __restrict__ Bl,
    float* __restrict__ C, __bf16* __restrict__ Ch, __bf16* __restrict__ Cl,
    int M, int N, int K,
    long sA1, long sA2, int divA, long sB1, int divB, long sC, float alpha) {
    constexpr int BM = 128, BK = 32;
    constexpr int NBUF = SPLIT ? 2 : 1;
    constexpr int NF = BN / 32;
    __shared__ __bf16 As[NBUF * BM * BK];
    __shared__ __bf16 Bs[NBUF * BN * BK];

    const int z = blockIdx.z;
    const long aoff = (long)(z / divA) * sA1 + (long)(z % divA) * sA2;
    const long boff = (long)(z / divB) * sB1;
    Ah += aoff; if (SPLIT) Al += aoff;
    Bh += boff; if (SPLIT) Bl += boff;

    const int tid = threadIdx.x;
    const int bm = blockIdx.y * BM, bn = blockIdx.x * BN;
    const int wave = tid >> 6, lane = tid & 63;
    const int wm = wave >> 1, wn = wave & 1;
    const int quad = lane >> 4, l16 = lane & 15;

    f32x4 acc[4][NF];
#pragma unroll
    for (int i = 0; i < 4; ++i)
#pragma unroll
        for (int j = 0; j < NF; ++j) acc[i][j] = (f32x4){0.f, 0.f, 0.f, 0.f};

    const int srow = lane >> 2;   // row within a 16-row DMA instr
    const int slot = lane & 3;    // 8-el chunk slot within row

    for (int k0 = 0; k0 < K; k0 += BK) {
        __syncthreads();  // previous iter's readers done before DMA overwrites
        // A tile: 128x32, 16 rows per wave-instr, 2 instrs/wave
#pragma unroll
        for (int i = 0; i < 2; ++i) {
            const int r0 = wave * 32 + i * 16;
            const int row = r0 + srow;
            const int chunk = slot ^ ((row >> 1) & 3);
            const long g = (long)(bm + row) * K + k0 + chunk * 8;
            gl_lds(Ah + g, &As[r0 * 32]);
            if (SPLIT) gl_lds(Al + g, &As[BM * BK + r0 * 32]);
        }
        if (BN == 128) {
#pragma unroll
            for (int i = 0; i < 2; ++i) {
                const int r0 = wave * 32 + i * 16;
                const int row = r0 + srow;
                const int chunk = slot ^ ((row >> 1) & 3);
                const long g = (long)(bn + row) * K + k0 + chunk * 8;
                gl_lds(Bh + g, &Bs[r0 * 32]);
                if (SPLIT) gl_lds(Bl + g, &Bs[BN * BK + r0 * 32]);
            }
        } else {  // BN == 64: one instr/wave
            const int r0 = wave * 16;
            const int row = r0 + srow;
            const int chunk = slot ^ ((row >> 1) & 3);
            const long g = (long)(bn + row) * K + k0 + chunk * 8;
            gl_lds(Bh + g, &Bs[r0 * 32]);
            if (SPLIT) gl_lds(Bl + g, &Bs[BN * BK + r0 * 32]);
        }
        __syncthreads();  // drains vmcnt (DMA) before frag reads

        bf16x8 a_h[4], a_l[4], b_h[NF], b_l[NF];
#pragma unroll
        for (int mi = 0; mi < 4; ++mi) {
            const int row = wm * 64 + mi * 16 + l16;
            const int off = row * 32 + ((quad ^ ((row >> 1) & 3)) * 8);
            a_h[mi] = *(const bf16x8*)&As[off];
            if (SPLIT) a_l[mi] = *(const bf16x8*)&As[BM * BK + off];
        }
#pragma unroll
        for (int ni = 0; ni < NF; ++ni) {
            const int row = wn * (BN / 2) + ni * 16 + l16;
            const int off = row * 32 + ((quad ^ ((row >> 1) & 3)) * 8);
            b_h[ni] = *(const bf16x8*)&Bs[off];
            if (SPLIT) b_l[ni] = *(const bf16x8*)&Bs[BN * BK + off];
        }
#pragma unroll
        for (int mi = 0; mi < 4; ++mi)
#pragma unroll
            for (int ni = 0; ni < NF; ++ni) {
                acc[mi][ni] = __builtin_amdgcn_mfma_f32_16x16x32_bf16(
                    a_h[mi], b_h[ni], acc[mi][ni], 0, 0, 0);
                if (SPLIT) {
                    acc[mi][ni] = __builtin_amdgcn_mfma_f32_16x16x32_bf16(
                        a_h[mi], b_l[ni], acc[mi][ni], 0, 0, 0);
                    acc[mi][ni] = __builtin_amdgcn_mfma_f32_16x16x32_bf16(
                        a_l[mi], b_h[ni], acc[mi][ni], 0, 0, 0);
                }
            }
    }

    C += (long)z * sC; Ch += (long)z * sC; Cl += (long)z * sC;
#pragma unroll
    for (int mi = 0; mi < 4; ++mi) {
        const int row0 = bm + wm * 64 + mi * 16 + quad * 4;
#pragma unroll
        for (int ni = 0; ni < NF; ++ni) {
            const int col = bn + wn * (BN / 2) + ni * 16 + l16;
#pragma unroll
            for (int r = 0; r < 4; ++r) {
                const float v = acc[mi][ni][r] * alpha;
                const long idx = (long)(row0 + r) * N + col;
                if (OUTM == 0) {
                    C[idx] = v;
                } else {
                    const __bf16 h = (__bf16)v;
                    Ch[idx] = h;
                    Cl[idx] = (__bf16)(v - (float)h);
                }
            }
        }
    }
}

// ---------------- blend + entropy + route -> bf16 attn_sel ------------------
__global__ __launch_bounds__(256) void blend_kernel(
    const float* __restrict__ S, const float* __restrict__ pos,
    const float* __restrict__ gating, const float* __restrict__ h_temp,
    float* __restrict__ heat, __bf16* __restrict__ Pb) {
    __shared__ float red[4];
    const int bn = blockIdx.x;
    const int b = bn >> 10, n = bn & 1023;
    const float* S0 = S + ((long)(b * 2 + 0) * NN_ + n) * NN_;
    const float* S1 = S + ((long)(b * 2 + 1) * NN_ + n) * NN_;
    const int tid = threadIdx.x;

    float4 l0 = *(const float4*)(S0 + tid * 4);
    float4 l1 = *(const float4*)(S1 + tid * 4);
    float4 pv = *(const float4*)(pos + (long)n * NN_ + tid * 4);

    float m0 = fmaxf(fmaxf(l0.x, l0.y), fmaxf(l0.z, l0.w));
    m0 = bred_max(m0, red);
    float e0x = expf(l0.x - m0), e0y = expf(l0.y - m0),
          e0z = expf(l0.z - m0), e0w = expf(l0.w - m0);
    float s0 = bred_sum(e0x + e0y + e0z + e0w, red);
    const float i0 = 1.f / s0;
    float m1 = fmaxf(fmaxf(l1.x, l1.y), fmaxf(l1.z, l1.w));
    m1 = bred_max(m1, red);
    float e1x = expf(l1.x - m1), e1y = expf(l1.y - m1),
          e1z = expf(l1.z - m1), e1w = expf(l1.w - m1);
    float s1 = bred_sum(e1x + e1y + e1z + e1w, red);
    const float i1 = 1.f / s1;

    const float g = 1.f / (1.f + expf(-gating[0]));
    const float cg = 1.f - g;

    float a0[4], a1[4];
    a0[0] = cg * (e0x * i0) + g * pv.x; a0[1] = cg * (e0y * i0) + g * pv.y;
    a0[2] = cg * (e0z * i0) + g * pv.z; a0[3] = cg * (e0w * i0) + g * pv.w;
    a1[0] = cg * (e1x * i1) + g * pv.x; a1[1] = cg * (e1y * i1) + g * pv.y;
    a1[2] = cg * (e1z * i1) + g * pv.z; a1[3] = cg * (e1w * i1) + g * pv.w;

    float ent0 = 0.f, ent1 = 0.f;
#pragma unroll
    for (int j = 0; j < 4; ++j) {
        ent0 -= a0[j] * logf(a0[j] + 1e-8f);
        ent1 -= a1[j] * logf(a1[j] + 1e-8f);
    }
    ent0 = bred_sum(ent0, red);
    ent1 = bred_sum(ent1, red);

    const float ht = h_temp[0];
    const float hm0 = 2.f - 2.f / (1.f + expf(-ht * ent0));
    const float hm1 = 2.f - 2.f / (1.f + expf(-ht * ent1));
    const bool fg = (hm0 >= hm1);
    if (tid == 0) heat[bn] = fg ? hm0 : hm1;

    bf16x4 o;
    o[0] = (__bf16)(fg ? a0[0] : a1[0]);
    o[1] = (__bf16)(fg ? a0[1] : a1[1]);
    o[2] = (__bf16)(fg ? a0[2] : a1[2]);
    o[3] = (__bf16)(fg ? a0[3] : a1[3]);
    *(bf16x4*)(Pb + ((long)b * NN_ + n) * NN_ + tid * 4) = o;
}

extern "C" void kernel_launch(void* const* d_in, const int* in_sizes, int n_in,
                              void* d_out, int out_size, void* d_ws, size_t ws_size,
                              hipStream_t stream) {
    const float* x      = (const float*)d_in[0];
    const float* y      = (const float*)d_in[1];
    const float* coords = (const float*)d_in[2];
    const float* U      = (const float*)d_in[3];
    const float* S1p    = (const float*)d_in[4];
    const float* S2p    = (const float*)d_in[5];
    const float* gating = (const float*)d_in[6];
    const float* h_temp = (const float*)d_in[7];
    const float* p_temp = (const float*)d_in[8];
    const float* pos_emb= (const float*)d_in[9];

    float* out  = (float*)d_out;
    float* heat = out + (long)NB * NN_ * ND;

    // workspace layout (~105 MB)
    char* ws = (char*)d_ws;
    const long MB = 1 << 20;
    float*  Sf  = (float*)(ws);              // [0,64M)   scores fp32
    float*  pos = (float*)(ws + 64 * MB);    // [64,68M)
    __bf16* Xh  = (__bf16*)(ws + 68 * MB);   // [68,72M)  x hi
    __bf16* Xl  = (__bf16*)(ws + 72 * MB);   // [72,76M)  x lo
    __bf16* XSh = (__bf16*)(ws + 76 * MB);   // [76,84M)  xs hi [2][8192][256]
    __bf16* XSl = (__bf16*)(ws + 84 * MB);   // [84,92M)  xs lo
    __bf16* Pb  = (__bf16*)(ws + 68 * MB);   // [68,84M)  attn_sel bf16 (after XS dead)
    __bf16* yt  = (__bf16*)(ws + 92 * MB);   // [92,96M)
    __bf16* Yh  = (__bf16*)(ws + 96 * MB);   // [96,100M)
    __bf16* Yl  = (__bf16*)(ws + 100 * MB);  // [100,104M)
    __bf16* Mh  = (__bf16*)(ws + 104 * MB);  // [2][256][256]
    __bf16* Ml  = Mh + 2 * 65536;

    const long ND2 = (long)NN_ * ND;   // 262144
    const long BND = (long)NB * ND2;   // 2097152

    pos_kernel<<<dim3(NN_), 256, 0, stream>>>(coords, pos_emb, p_temp, pos);
    conv_split<<<dim3(2048), 256, 0, stream>>>(x, Xh, Xl, (int)(BND / 4));
    prep_y<<<dim3(16, 4, NB), 256, 0, stream>>>(y, yt, Yh, Yl);
    build_M<<<dim3(ND), ND, 0, stream>>>(U, S1p, S2p, Mh, Ml);

    // xs_k = x @ M_k  (z=k) -> XS [2][8192][256]
    mgemm<64, true, 1><<<dim3(4, 64, 2), 256, 0, stream>>>(
        Xh, Xl, Mh, Ml, nullptr, XSh, XSl, NB * NN_, ND, ND,
        0, 0, 1, 65536, 1, BND, 1.0f);

    // scores: S[b][k] = (xs_k[b] @ y[b]^T) * D^-0.5 ; z = b*2+k
    mgemm<128, true, 0><<<dim3(8, 8, NB * 2), 256, 0, stream>>>(
        XSh, XSl, Yh, Yl, Sf, nullptr, nullptr, NN_, NN_, ND,
        ND2, BND, 2, ND2, 2, (long)NN_ * NN_, 0.0625f);

    // blend + entropy + route -> Pb (bf16), heat
    blend_kernel<<<dim3(NB * NN_), 256, 0, stream>>>(Sf, pos, gating, h_temp, heat, Pb);

    // out[b] = Pb[b] @ yt[b]^T   M=1024, N=256, K=1024
    mgemm<64, false, 0><<<dim3(4, 8, NB), 256, 0, stream>>>(
        Pb, nullptr, yt, nullptr, out, nullptr, nullptr, NN_, ND, NN_,
        (long)NN_ * NN_, 0, 1, ND2, 1, ND2, 1.0f);

    (void)in_sizes; (void)n_in; (void)out_size; (void)ws_size;
}